// Round 5
// baseline (215.920 us; speedup 1.0000x reference)
//
#include <hip/hip_runtime.h>
#include <limits.h>
#include <math.h>
#include <stdint.h>

#define WOS_ZERO_TOL 1e-6f
#define STRIDE 58   // even, 8B-aligned rows (58*4=232B): phase-2 reads float2
                    // pairs (27 ds_read_b64 instead of 54 b32). Bank map:
                    // row base word = ncp*58 mod 32 = ncp*26 mod 32; period-16
                    // cycle -> the 16 channel rows land on 16 DISTINCT banks.

// One wave (64 lanes) per pixel.  Skeleton = round-4 (== verified round-1
// structure).  SINGLE change this round: rank keys are u32 (order-preserving
// float map) instead of u64, with the compare+accumulate asm-pinned to the
// full-rate 2-op idiom  v_cmp_gt_u32 vcc / v_addc_co_u32.  Motivation:
// R4 proved the u64 path was already emitting the lean idiom yet still costs
// ~9.6k VALU-cyc/wave for ~2.3k static instrs -> v_cmp_gt_u64 is multi-cycle;
// u32 compares are full-rate and b128 key reads now carry FOUR keys/issue
// (14 reads/nc instead of 27).  R2/R3's u32 regressions were confounded
// (cndmask codegen, stride-56 bank folding, extra fences) — all avoided here.
// Stability vs jnp's stable argsort: exact tie DETECTOR — sum of ranks over
// all lanes/nc == 16*C(54,2) == 22896 iff no exact f32 tie occurred (a tied
// pair contributes 0 instead of 1; can never overcount).  On mismatch
// (~never; validated harness-pass in R2/R3), wave-uniform fallback redoes
// all 16 nc with the exact stable rank (ob_dp + (dp<lane)) > ob_mine, which
// is algebraically identical to the u64 (ob :: 63-lane) key ordering.
// Phase 1 stores the 1-byte rank per (nc,lane) + zeroed weight scattered to
//   its sorted slot; winner value re-derived bit-exactly in phase 3.
// Phase 2 (transposed): lane nc = lane&15 walks the 54 sorted weights once —
//   sequential f32 adds, association order identical to np.cumsum.
// Phase 3: unique lane with rank==rstar recomputes inp+mask[nc][lane];
//   lanes<16 do one coalesced 64B store.
// LDS: 14848 + 1024 + 3584 = 19456 B -> 8 blocks/CU (32 waves/CU).
__global__ __launch_bounds__(256, 8) void wos_kernel(
    const float* __restrict__ x,       // (8,3,64,64)
    const float* __restrict__ mask,    // (16,54)
    const float* __restrict__ weight,  // (16,54)
    const float* __restrict__ bias,    // (16,1)
    float* __restrict__ out)           // flat: [pixel*16 + nc]
{
    __shared__ float s_ws[4][16][STRIDE];                  // 14848 B
    __shared__ __align__(16) uint32_t s_key[4][64];        //  1024 B
    __shared__ unsigned char s_rank[4][16][56];            //  3584 B

    const int lane = threadIdx.x & 63;
    const int wid  = threadIdx.x >> 6;
    const int p    = blockIdx.x * 4 + wid;   // pixel in [0, 32768)
    const int b    = p >> 12;
    const int l    = p & 4095;
    const int h    = l >> 6;
    const int w    = l & 63;

    // Gather this lane's patch value (zero padding at borders).
    float inp = 0.0f;
    if (lane < 54) {
        int dm  = (lane < 27) ? lane : lane - 27;
        int c   = dm / 9;
        int rem = dm - 9 * c;
        int di  = rem / 3;
        int dj  = rem - 3 * di;
        int hh  = h + di - 1;
        int ww  = w + dj - 1;
        if (hh >= 0 && hh < 64 && ww >= 0 && ww < 64) {
            float v = x[((b * 3 + c) << 12) + (hh << 6) + ww];
            inp = (lane < 27) ? v : -v;
        }
    }

    const int midx = (lane < 54) ? lane : 0;   // clamped index: branchless loads

    // Software prefetch of next nc's mask/weight (L1-hot).
    float mk_next = mask[midx];
    float wv_next = weight[midx];

    // ---- Phase 1: u32 rank via LDS-broadcast key quads (asm-pinned) ----
    uint32_t ranksum = 0;
    #pragma unroll 1
    for (int nc = 0; nc < 16; ++nc) {
        const float mk = mk_next;
        const float wv = wv_next;
        if (nc < 15) {
            mk_next = mask[(nc + 1) * 54 + midx];
            wv_next = weight[(nc + 1) * 54 + midx];
        }
        const float mxv  = inp + mk;               // idle lanes: junk, unused
        const float wsel = (wv > WOS_ZERO_TOL) ? wv : 0.0f;

        // Order-preserving uint32 map of float order (no NaNs here).
        // Real (finite) values map into 0x00800000..0xFF7FFFFF.
        const int      bits = __float_as_int(mxv);
        const uint32_t ob   = (uint32_t)(bits ^ ((bits >> 31) | 0x80000000));
        // Pad slots (>=54) hold 0: below every real key, never counted.
        const uint32_t stk  = (lane < 54) ? ob : 0u;
        // Idle lanes compare as UINT_MAX: rank 0, contribute 0 to checksum.
        const uint32_t myk  = (lane < 54) ? ob : 0xFFFFFFFFu;

        s_key[wid][lane] = stk;
        // Fence: reads below are a different access pattern than the store;
        // keep program order (store precedes the broadcast reads).
        asm volatile("" ::: "memory");

        // rank = #{dp in 0..55 : key_dp > key_mine}. Uniform-address LDS
        // b128 reads broadcast FOUR keys per issue; per key exactly
        // v_cmp_gt_u32 (full-rate) + v_addc_co_u32.
        const uint4* kp = (const uint4*)(&s_key[wid][0]);
        uint32_t rank = 0;
        #pragma unroll
        for (int i = 0; i < 14; ++i) {
            uint4 kk = kp[i];
            asm volatile(
                "v_cmp_gt_u32 vcc, %2, %1\n\t"
                "v_addc_co_u32 %0, vcc, 0, %0, vcc\n\t"
                "v_cmp_gt_u32 vcc, %3, %1\n\t"
                "v_addc_co_u32 %0, vcc, 0, %0, vcc\n\t"
                "v_cmp_gt_u32 vcc, %4, %1\n\t"
                "v_addc_co_u32 %0, vcc, 0, %0, vcc\n\t"
                "v_cmp_gt_u32 vcc, %5, %1\n\t"
                "v_addc_co_u32 %0, vcc, 0, %0, vcc"
                : "+v"(rank)
                : "v"(myk), "v"(kk.x), "v"(kk.y), "v"(kk.z), "v"(kk.w)
                : "vcc");
        }
        ranksum += rank;

        // If no ties, active lanes get distinct ranks covering exactly 0..53.
        if (lane < 54) {
            s_ws[wid][nc][rank]   = wsel;
            s_rank[wid][nc][lane] = (unsigned char)rank;
        }
    }

    // ---- Tie checksum: sum of all ranks == 16*1431 iff no tie anywhere ----
    {
        uint32_t tot = ranksum;
        #pragma unroll
        for (int s = 1; s < 64; s <<= 1) tot += __shfl_xor(tot, s, 64);
        if (tot != 22896u) {
            // Exact stable-rank fallback (wave-uniform branch, ~never taken).
            #pragma unroll 1
            for (int nc = 0; nc < 16; ++nc) {
                const float mk   = mask[nc * 54 + midx];
                const float wv   = weight[nc * 54 + midx];
                const float mxv  = inp + mk;
                const float wsel = (wv > WOS_ZERO_TOL) ? wv : 0.0f;
                const int      bits = __float_as_int(mxv);
                const uint32_t ob   = (uint32_t)(bits ^ ((bits >> 31) | 0x80000000));
                const uint32_t stk  = (lane < 54) ? ob : 0u;
                const uint32_t myk  = (lane < 54) ? ob : 0xFFFFFFFFu;
                s_key[wid][lane] = stk;
                asm volatile("" ::: "memory");
                uint32_t rank = 0;
                #pragma unroll 1
                for (int dp = 0; dp < 54; ++dp) {
                    // stable: greater, or equal with earlier lane index.
                    // ob+1 never overflows (real ob <= 0xFF7FFFFF).
                    uint32_t adj = s_key[wid][dp] + ((dp < lane) ? 1u : 0u);
                    rank += (adj > myk) ? 1u : 0u;
                }
                if (lane < 54) {
                    s_ws[wid][nc][rank]   = wsel;
                    s_rank[wid][nc][lane] = (unsigned char)rank;
                }
                asm volatile("" ::: "memory");
            }
        }
    }

    // Phase 1 is done with s_key: reuse its space for phase-2/3 scratch.
    asm volatile("" ::: "memory");
    int*   s_r   = (int*)(&s_key[wid][0]);     // 16 ints  (bytes 0..63)
    float* s_out = (float*)(&s_key[wid][16]);  // 16 floats (bytes 64..127)

    // ---- Phase 2: transposed sequential scan, lane = channel ----
    {
        const int   ncp = lane & 15;      // lanes 16..63 run redundant copies
        const float bv  = bias[ncp];
        // Row base (wid*16+ncp)*232 B is 8B-aligned -> float2 LDS reads.
        const float2* wp2 = (const float2*)(&s_ws[wid][ncp][0]);
        float acc   = 0.0f;
        int   rstar = -1;
        #pragma unroll
        for (int i = 0; i < 27; ++i) {
            float2 wpair = wp2[i];
            acc += wpair.x;                               // exact cumsum order
            rstar = (wpair.x > 0.0f && acc <= bv) ? (2 * i)     : rstar;
            acc += wpair.y;
            rstar = (wpair.y > 0.0f && acc <= bv) ? (2 * i + 1) : rstar;
        }
        if (rstar < 0) {                  // fallback: first nz (never taken:
            #pragma unroll 1              // first nz weight <=1 < bias~13.5)
            for (int r = 53; r >= 0; --r) {
                float wr = s_ws[wid][ncp][r];
                rstar = (wr > 0.0f) ? r : rstar;
            }
            if (rstar < 0) rstar = 0;
        }
        if (lane < 16) s_r[ncp] = rstar;
    }

    // ---- Phase 3: winner lane re-derives its value, coalesced store ----
    {
        asm volatile("" ::: "memory");
        #pragma unroll 1
        for (int nc = 0; nc < 16; ++nc) {
            const int   rk = (int)s_rank[wid][nc][midx];
            const int   rs = s_r[nc];                    // uniform broadcast
            const float mk = mask[nc * 54 + midx];       // L1-hot reload
            if (lane < 54 && rk == rs)
                s_out[nc] = inp + mk;    // bit-exact re-derivation of mxv
        }
        asm volatile("" ::: "memory");
        if (lane < 16) out[p * 16 + lane] = s_out[lane];
    }
}

extern "C" void kernel_launch(void* const* d_in, const int* in_sizes, int n_in,
                              void* d_out, int out_size, void* d_ws, size_t ws_size,
                              hipStream_t stream) {
    const float* x      = (const float*)d_in[0];
    const float* mask   = (const float*)d_in[1];
    const float* weight = (const float*)d_in[2];
    const float* bias   = (const float*)d_in[3];
    float* out = (float*)d_out;

    // 32768 pixels, 4 waves (pixels) per 256-thread block -> 8192 blocks
    wos_kernel<<<dim3(8192), dim3(256), 0, stream>>>(x, mask, weight, bias, out);
}

// Round 6
// 190.970 us; speedup vs baseline: 1.1307x; 1.1307x over previous
//
#include <hip/hip_runtime.h>
#include <limits.h>
#include <math.h>
#include <stdint.h>

#define WOS_ZERO_TOL 1e-6f
#define STRIDE 57   // odd stride: 16 channel rows start on distinct banks

// CHAMPION REVERT (round-1 kernel, measured 148.7us rocprof / 191us harness).
// Five rounds of perturbation (u32 keys x3, asm-pinned idioms x2, stride
// variants, fence variants, float2 phase-2) were all neutral-to-negative;
// the u32/checksum family carries a reproducible ~15-20% penalty of
// undiagnosed origin. This is the bit-for-bit best-known variant.
//
// One wave (64 lanes) per pixel.
// Phase 1 (per nc): lane d owns candidate d (d<27: patch value, d>=27:
//   negated). Stable descending rank via u64 key (ordered_float :: 63-lane)
//   — bit-exact vs jnp stable argsort. Keys broadcast through LDS: each lane
//   writes its full u64 key to s_key[wid][lane]; the rank loop reads key
//   PAIRS via ds_read_b128 at wave-uniform addresses (hardware broadcast,
//   conflict-free, LDS pipe). Per key the VALU cost is v_cmp_gt_u64 + v_addc.
// Phase 1 stores only the 1-byte rank per (nc, lane) plus the zeroed weight
//   scattered to its sorted slot; the winner's value is re-derived
//   bit-exactly in phase 3 as inp + mask[nc][lane] (same op, same operands).
// Phase 2 (transposed): lane nc = lane&15 walks the 54 sorted weights once —
//   sequential f32 adds, association order identical to np.cumsum.
//   rstar = last r with (w>0 && acc<=bias); first-nz fallback never taken
//   (first nz weight <= 1 < bias ~= 13.5).
// Phase 3: per nc, all lanes read rstar (uniform LDS broadcast) and their
//   rank byte; the unique lane with rank==rstar recomputes its value and
//   writes it to s_out; lanes<16 do one coalesced 64B store.
// LDS: 14592 + 2048 + 3584 = 20224 B (rounds to 20480) -> 8 blocks/CU
//   (32 waves/CU, the architectural cap).
// s_r/s_out alias the dead s_key region (phase 1 finished with it; same
//   wave, in-order LDS). asm memory fences pin the type-punned ordering.
__global__ __launch_bounds__(256, 8) void wos_kernel(
    const float* __restrict__ x,       // (8,3,64,64)
    const float* __restrict__ mask,    // (16,54)
    const float* __restrict__ weight,  // (16,54)
    const float* __restrict__ bias,    // (16,1)
    float* __restrict__ out)           // flat: [pixel*16 + nc]
{
    __shared__ float s_ws[4][16][STRIDE];                    // 14592 B
    __shared__ __align__(16) unsigned long long s_key[4][64]; //  2048 B
    __shared__ unsigned char s_rank[4][16][56];              //  3584 B

    const int lane = threadIdx.x & 63;
    const int wid  = threadIdx.x >> 6;
    const int p    = blockIdx.x * 4 + wid;   // pixel in [0, 32768)
    const int b    = p >> 12;
    const int l    = p & 4095;
    const int h    = l >> 6;
    const int w    = l & 63;

    // Gather this lane's patch value (zero padding at borders).
    float inp = 0.0f;
    if (lane < 54) {
        int dm  = (lane < 27) ? lane : lane - 27;
        int c   = dm / 9;
        int rem = dm - 9 * c;
        int di  = rem / 3;
        int dj  = rem - 3 * di;
        int hh  = h + di - 1;
        int ww  = w + dj - 1;
        if (hh >= 0 && hh < 64 && ww >= 0 && ww < 64) {
            float v = x[((b * 3 + c) << 12) + (hh << 6) + ww];
            inp = (lane < 27) ? v : -v;
        }
    }

    const uint32_t inv_lane = (uint32_t)(63 - lane);
    const int midx = (lane < 54) ? lane : 0;   // clamped index: branchless loads

    // Software prefetch of next nc's mask/weight (L1-hot, hides load latency).
    float mk_next = mask[midx];
    float wv_next = weight[midx];

    // ---- Phase 1: rank via LDS-broadcast key-pair compares + scatter ----
    #pragma unroll 1
    for (int nc = 0; nc < 16; ++nc) {
        const float mk = mk_next;
        const float wv = wv_next;
        if (nc < 15) {
            mk_next = mask[(nc + 1) * 54 + midx];
            wv_next = weight[(nc + 1) * 54 + midx];
        }
        const float mxv  = (lane < 54) ? (inp + mk) : -INFINITY;
        const float wsel = (wv > WOS_ZERO_TOL) ? wv : 0.0f;

        // Order-preserving uint32 map of float order (no NaNs here).
        const int      bits = __float_as_int(mxv);
        const uint32_t ob   = (uint32_t)(bits ^ ((bits >> 31) | 0x80000000));
        // 64-bit stable key: value major, (63-lane) minor -> distinct keys,
        // strict > reproduces jnp's stable descending argsort exactly.
        const uint64_t myk  = ((uint64_t)ob << 32) | inv_lane;

        // Publish key; same-wave RAW/WAR ordering is enforced by in-order
        // per-wave LDS + compiler lgkmcnt waits (each wave owns slice [wid]).
        s_key[wid][lane] = myk;
        // Fence: the b128 reads below are a different TBAA type than the
        // u64 store; keep program order (store must precede the reads).
        asm volatile("" ::: "memory");

        // rank = #{dp in 0..53 : key_dp > key_mine}. Uniform-address LDS
        // b128 reads broadcast two keys per issue; VALU per key is exactly
        // v_cmp_gt_u64 vcc + v_addc.
        const ulonglong2* kp = (const ulonglong2*)(&s_key[wid][0]);
        uint32_t r0 = 0, r1 = 0;
        #pragma unroll
        for (int i = 0; i < 27; ++i) {
            ulonglong2 kk = kp[i];
            r0 += (kk.x > myk) ? 1u : 0u;
            r1 += (kk.y > myk) ? 1u : 0u;
        }
        const uint32_t rank = r0 + r1;

        // Active lanes get distinct ranks covering exactly 0..53 (idle
        // lanes' -INF keys rank below all real keys; their rank is junk
        // and discarded by the guard).
        if (lane < 54) {
            s_ws[wid][nc][rank]   = wsel;
            s_rank[wid][nc][lane] = (unsigned char)rank;
        }
    }

    // Phase 1 is done with s_key: reuse its space for phase-2/3 scratch.
    asm volatile("" ::: "memory");
    int*   s_r   = (int*)(&s_key[wid][0]);     // 16 ints  (bytes 0..63)
    float* s_out = (float*)(&s_key[wid][16]);  // 16 floats (bytes 128..191)

    // ---- Phase 2: transposed sequential scan, lane = channel ----
    {
        const int   ncp = lane & 15;      // lanes 16..63 run redundant copies
        const float bv  = bias[ncp];
        float acc   = 0.0f;
        int   rstar = -1;
        #pragma unroll
        for (int r = 0; r < 54; ++r) {
            float wr = s_ws[wid][ncp][r];
            acc += wr;                                  // exact np.cumsum order
            rstar = (wr > 0.0f && acc <= bv) ? r : rstar;  // last nz, acc<=bias
        }
        if (rstar < 0) {                  // fallback: first nz (never taken:
            #pragma unroll 1              // first nz weight <=1 < bias~13.5)
            for (int r = 53; r >= 0; --r) {
                float wr = s_ws[wid][ncp][r];
                rstar = (wr > 0.0f) ? r : rstar;
            }
            if (rstar < 0) rstar = 0;
        }
        if (lane < 16) s_r[ncp] = rstar;
    }

    // ---- Phase 3: winner lane re-derives its value, coalesced store ----
    {
        asm volatile("" ::: "memory");
        #pragma unroll 1
        for (int nc = 0; nc < 16; ++nc) {
            const int   rk = (int)s_rank[wid][nc][midx];
            const int   rs = s_r[nc];                    // uniform broadcast
            const float mk = mask[nc * 54 + midx];       // L1-hot reload
            if (lane < 54 && rk == rs)
                s_out[nc] = inp + mk;    // bit-exact re-derivation of mxv
        }
        asm volatile("" ::: "memory");
        if (lane < 16) out[p * 16 + lane] = s_out[lane];
    }
}

extern "C" void kernel_launch(void* const* d_in, const int* in_sizes, int n_in,
                              void* d_out, int out_size, void* d_ws, size_t ws_size,
                              hipStream_t stream) {
    const float* x      = (const float*)d_in[0];
    const float* mask   = (const float*)d_in[1];
    const float* weight = (const float*)d_in[2];
    const float* bias   = (const float*)d_in[3];
    float* out = (float*)d_out;

    // 32768 pixels, 4 waves (pixels) per 256-thread block -> 8192 blocks
    wos_kernel<<<dim3(8192), dim3(256), 0, stream>>>(x, mask, weight, bias, out);
}